// Round 1
// baseline (192.220 us; speedup 1.0000x reference)
//
#include <hip/hip_runtime.h>

#define N_VARS 50000
#define N_TX   200000
#define DSZ    32

// out = theta (residual initialization), vectorized float4
__global__ void copy_theta_kernel(const float4* __restrict__ theta,
                                  float4* __restrict__ out, int n4) {
    int i = blockIdx.x * blockDim.x + threadIdx.x;
    int stride = gridDim.x * blockDim.x;
    for (; i < n4; i += stride) out[i] = theta[i];
}

// One wave (64 lanes) per transform e:
//   lane l reads W[e] flat float4 at it*256 + l*4  -> row i = it*8 + (l>>3), col j0 = (l&7)*4
//   per-instruction the wave reads a contiguous 1KiB block of W (streaming-friendly)
//   x gathered once per transform; 8-lane shfl_xor reduce; leader atomically adds -y.
__global__ void transform_scatter_kernel(const float* __restrict__ theta,
                                         const float* __restrict__ W,
                                         const float* __restrict__ b,
                                         const int* __restrict__ src,
                                         const int* __restrict__ tgt,
                                         float* __restrict__ out) {
    const int lane   = threadIdx.x & 63;
    const int waveId = (blockIdx.x * blockDim.x + threadIdx.x) >> 6;
    const int nWaves = (gridDim.x * blockDim.x) >> 6;
    const int j0     = (lane & 7) << 2;   // starting col of this lane's 4-wide slice
    const int rsub   = lane >> 3;         // row offset within the 8-row group

    for (int e = waveId; e < N_TX; e += nWaves) {
        const int s = src[e];
        const int t = tgt[e];

        // x[j0..j0+4) for this transform's source variable (aligned 16B)
        const float4 xv = *reinterpret_cast<const float4*>(theta + (size_t)s * DSZ + j0);

        const float* We = W + (size_t)e * (DSZ * DSZ);
        const float* be = b + (size_t)e * DSZ;
        float* oute = out + (size_t)t * DSZ;

        #pragma unroll
        for (int it = 0; it < 4; ++it) {
            const float4 wv =
                *reinterpret_cast<const float4*>(We + it * 256 + lane * 4);
            float p = wv.x * xv.x + wv.y * xv.y + wv.z * xv.z + wv.w * xv.w;
            // reduce across the 8 lanes sharing the same output row
            p += __shfl_xor(p, 1);
            p += __shfl_xor(p, 2);
            p += __shfl_xor(p, 4);
            if ((lane & 7) == 0) {
                const int i = it * 8 + rsub;
                const float y = p + be[i];
                atomicAdd(&oute[i], -y);   // resid = theta - preds
            }
        }
    }
}

extern "C" void kernel_launch(void* const* d_in, const int* in_sizes, int n_in,
                              void* d_out, int out_size, void* d_ws, size_t ws_size,
                              hipStream_t stream) {
    const float* theta = (const float*)d_in[0];
    const float* W     = (const float*)d_in[1];
    const float* b     = (const float*)d_in[2];
    const int*   src   = (const int*)d_in[3];
    const int*   tgt   = (const int*)d_in[4];
    float* out = (float*)d_out;

    // 1) out = theta
    const int n4 = (N_VARS * DSZ) / 4;               // 400,000 float4s
    const int cpBlocks = 1024;
    copy_theta_kernel<<<cpBlocks, 256, 0, stream>>>(
        (const float4*)theta, (float4*)out, n4);

    // 2) scatter transforms (grid-stride by wave; 2048 blocks x 256 = 8192 waves)
    const int txBlocks = 2048;
    transform_scatter_kernel<<<txBlocks, 256, 0, stream>>>(
        theta, W, b, src, tgt, out);
}

// Round 2
// 164.897 us; speedup vs baseline: 1.1657x; 1.1657x over previous
//
#include <hip/hip_runtime.h>

#define N_VARS 50000
#define N_TX   200000
#define DSZ    32

typedef float f32x4 __attribute__((ext_vector_type(4)));

// out = theta (residual initialization), vectorized float4
__global__ void copy_theta_kernel(const float4* __restrict__ theta,
                                  float4* __restrict__ out, int n4) {
    int i = blockIdx.x * blockDim.x + threadIdx.x;
    int stride = gridDim.x * blockDim.x;
    for (; i < n4; i += stride) out[i] = theta[i];
}

// One wave per contiguous chunk of CHUNK edges, 2 edges per loop body.
// Lane l covers W flat float4 at lane*4 within each 1KiB quarter:
//   row i = it*8 + (l>>3), cols j0 = (l&7)*4.
// After 3x shfl_xor all 8 lanes of a group hold the row sum; lanes with
// (l&7)<4 each write one distinct row: row = (l&3)*8 + (l>>3).
__global__ __launch_bounds__(256)
void transform_scatter_kernel(const float* __restrict__ theta,
                              const float* __restrict__ W,
                              const float* __restrict__ bia,
                              const int* __restrict__ src,
                              const int* __restrict__ tgt,
                              float* __restrict__ out) {
    const int CHUNK = 26;  // even -> pair loop only (N_TX multiple of 2 per chunk)
    const int lane = threadIdx.x & 63;
    const int wave = (blockIdx.x * blockDim.x + threadIdx.x) >> 6;

    int e0 = wave * CHUNK;
    if (e0 >= N_TX) return;
    const int e1 = (e0 + CHUNK < N_TX) ? e0 + CHUNK : N_TX;

    const int j0    = (lane & 7) << 2;  // this lane's 4-wide col slice
    const int g     = lane >> 3;        // row-group within the 8-row band
    const bool wr   = (lane & 7) < 4;   // writer lanes (one per (it,g))
    const int myIt  = lane & 3;
    const int myRow = myIt * 8 + g;     // output row this lane owns

    int e = e0;
    for (; e + 1 < e1; e += 2) {
        const int sA = src[e],     tA = tgt[e];
        const int sB = src[e + 1], tB = tgt[e + 1];

        const f32x4 xA = *reinterpret_cast<const f32x4*>(theta + (size_t)sA * DSZ + j0);
        const f32x4 xB = *reinterpret_cast<const f32x4*>(theta + (size_t)sB * DSZ + j0);

        const f32x4* WA = reinterpret_cast<const f32x4*>(W + (size_t)e * (DSZ * DSZ));
        const f32x4* WB = WA + 256;  // next edge's matrix (1024 floats = 256 f32x4)

        // issue all 8 W loads (8 KiB in flight) — nontemporal: W has zero reuse
        const f32x4 a0 = __builtin_nontemporal_load(WA +   0 + lane);
        const f32x4 a1 = __builtin_nontemporal_load(WA +  64 + lane);
        const f32x4 a2 = __builtin_nontemporal_load(WA + 128 + lane);
        const f32x4 a3 = __builtin_nontemporal_load(WA + 192 + lane);
        const f32x4 c0 = __builtin_nontemporal_load(WB +   0 + lane);
        const f32x4 c1 = __builtin_nontemporal_load(WB +  64 + lane);
        const f32x4 c2 = __builtin_nontemporal_load(WB + 128 + lane);
        const f32x4 c3 = __builtin_nontemporal_load(WB + 192 + lane);

        const float biasA = bia[(size_t)e * DSZ + myRow];
        const float biasB = bia[(size_t)(e + 1) * DSZ + myRow];

        float pA0 = a0.x * xA.x + a0.y * xA.y + a0.z * xA.z + a0.w * xA.w;
        float pA1 = a1.x * xA.x + a1.y * xA.y + a1.z * xA.z + a1.w * xA.w;
        float pA2 = a2.x * xA.x + a2.y * xA.y + a2.z * xA.z + a2.w * xA.w;
        float pA3 = a3.x * xA.x + a3.y * xA.y + a3.z * xA.z + a3.w * xA.w;
        float pB0 = c0.x * xB.x + c0.y * xB.y + c0.z * xB.z + c0.w * xB.w;
        float pB1 = c1.x * xB.x + c1.y * xB.y + c1.z * xB.z + c1.w * xB.w;
        float pB2 = c2.x * xB.x + c2.y * xB.y + c2.z * xB.z + c2.w * xB.w;
        float pB3 = c3.x * xB.x + c3.y * xB.y + c3.z * xB.z + c3.w * xB.w;

        #pragma unroll
        for (int m = 1; m <= 4; m <<= 1) {
            pA0 += __shfl_xor(pA0, m); pA1 += __shfl_xor(pA1, m);
            pA2 += __shfl_xor(pA2, m); pA3 += __shfl_xor(pA3, m);
            pB0 += __shfl_xor(pB0, m); pB1 += __shfl_xor(pB1, m);
            pB2 += __shfl_xor(pB2, m); pB3 += __shfl_xor(pB3, m);
        }

        if (wr) {
            const float vA = (myIt == 0) ? pA0 : (myIt == 1) ? pA1 : (myIt == 2) ? pA2 : pA3;
            const float vB = (myIt == 0) ? pB0 : (myIt == 1) ? pB1 : (myIt == 2) ? pB2 : pB3;
            atomicAdd(out + (size_t)tA * DSZ + myRow, -(vA + biasA));
            atomicAdd(out + (size_t)tB * DSZ + myRow, -(vB + biasB));
        }
    }

    // tail (defensive; CHUNK parity makes this dead for these sizes)
    for (; e < e1; ++e) {
        const int s = src[e], t = tgt[e];
        const f32x4 xv = *reinterpret_cast<const f32x4*>(theta + (size_t)s * DSZ + j0);
        const f32x4* We = reinterpret_cast<const f32x4*>(W + (size_t)e * (DSZ * DSZ));
        const float biasv = bia[(size_t)e * DSZ + myRow];
        float p0, p1, p2, p3;
        {
            const f32x4 a0 = __builtin_nontemporal_load(We +   0 + lane);
            const f32x4 a1 = __builtin_nontemporal_load(We +  64 + lane);
            const f32x4 a2 = __builtin_nontemporal_load(We + 128 + lane);
            const f32x4 a3 = __builtin_nontemporal_load(We + 192 + lane);
            p0 = a0.x * xv.x + a0.y * xv.y + a0.z * xv.z + a0.w * xv.w;
            p1 = a1.x * xv.x + a1.y * xv.y + a1.z * xv.z + a1.w * xv.w;
            p2 = a2.x * xv.x + a2.y * xv.y + a2.z * xv.z + a2.w * xv.w;
            p3 = a3.x * xv.x + a3.y * xv.y + a3.z * xv.z + a3.w * xv.w;
        }
        #pragma unroll
        for (int m = 1; m <= 4; m <<= 1) {
            p0 += __shfl_xor(p0, m); p1 += __shfl_xor(p1, m);
            p2 += __shfl_xor(p2, m); p3 += __shfl_xor(p3, m);
        }
        if (wr) {
            const float v = (myIt == 0) ? p0 : (myIt == 1) ? p1 : (myIt == 2) ? p2 : p3;
            atomicAdd(out + (size_t)t * DSZ + myRow, -(v + biasv));
        }
    }
}

extern "C" void kernel_launch(void* const* d_in, const int* in_sizes, int n_in,
                              void* d_out, int out_size, void* d_ws, size_t ws_size,
                              hipStream_t stream) {
    const float* theta = (const float*)d_in[0];
    const float* W     = (const float*)d_in[1];
    const float* b     = (const float*)d_in[2];
    const int*   src   = (const int*)d_in[3];
    const int*   tgt   = (const int*)d_in[4];
    float* out = (float*)d_out;

    // 1) out = theta
    const int n4 = (N_VARS * DSZ) / 4;
    copy_theta_kernel<<<1024, 256, 0, stream>>>((const float4*)theta, (float4*)out, n4);

    // 2) scatter transforms: ceil(200000/26)=7693 waves -> 1924 blocks x 4 waves
    const int CHUNK = 26;
    const int nWaves = (N_TX + CHUNK - 1) / CHUNK;
    const int blocks = (nWaves + 3) / 4;  // 4 waves per 256-thread block
    transform_scatter_kernel<<<blocks, 256, 0, stream>>>(theta, W, b, src, tgt, out);
}

// Round 3
// 159.666 us; speedup vs baseline: 1.2039x; 1.0328x over previous
//
#include <hip/hip_runtime.h>

#define N_VARS 50000
#define N_TX   200000
#define DSZ    32

// 4000 waves * 50 edges = 200000 exactly; 50 even -> pair loop only.
#define NWAVES 4000
#define CHUNK  50

typedef float f32x4 __attribute__((ext_vector_type(4)));

// out = theta (residual initialization), vectorized float4
__global__ void copy_theta_kernel(const float4* __restrict__ theta,
                                  float4* __restrict__ out, int n4) {
    int i = blockIdx.x * blockDim.x + threadIdx.x;
    int stride = gridDim.x * blockDim.x;
    for (; i < n4; i += stride) out[i] = theta[i];
}

// One wave per contiguous chunk of CHUNK edges, 2 edges per loop body.
// Lane l covers W flat float4 at lane*4 within each 1KiB quarter:
//   row i = it*8 + (l>>3), cols j0 = (l&7)*4.
// After 3x shfl_xor all 8 lanes of a group hold the row sum; lanes with
// (l&7)<4 each write one distinct row: row = (l&3)*8 + (l>>3).
__global__ __launch_bounds__(256)
void transform_scatter_kernel(const float* __restrict__ theta,
                              const float* __restrict__ W,
                              const float* __restrict__ bia,
                              const int* __restrict__ src,
                              const int* __restrict__ tgt,
                              float* __restrict__ out) {
    const int lane = threadIdx.x & 63;
    const int wave = (blockIdx.x * blockDim.x + threadIdx.x) >> 6;

    const int e0 = wave * CHUNK;          // always < N_TX by construction
    const int e1 = e0 + CHUNK;

    const int j0    = (lane & 7) << 2;  // this lane's 4-wide col slice
    const int g     = lane >> 3;        // row-group within the 8-row band
    const bool wr   = (lane & 7) < 4;   // writer lanes (one per (it,g))
    const int myIt  = lane & 3;
    const int myRow = myIt * 8 + g;     // output row this lane owns

    for (int e = e0; e < e1; e += 2) {
        const int sA = src[e],     tA = tgt[e];
        const int sB = src[e + 1], tB = tgt[e + 1];

        const f32x4 xA = *reinterpret_cast<const f32x4*>(theta + (size_t)sA * DSZ + j0);
        const f32x4 xB = *reinterpret_cast<const f32x4*>(theta + (size_t)sB * DSZ + j0);

        const f32x4* WA = reinterpret_cast<const f32x4*>(W + (size_t)e * (DSZ * DSZ));
        const f32x4* WB = WA + 256;  // next edge's matrix (1024 floats = 256 f32x4)

        // issue all 8 W loads (8 KiB in flight) — nontemporal: W has zero reuse
        const f32x4 a0 = __builtin_nontemporal_load(WA +   0 + lane);
        const f32x4 a1 = __builtin_nontemporal_load(WA +  64 + lane);
        const f32x4 a2 = __builtin_nontemporal_load(WA + 128 + lane);
        const f32x4 a3 = __builtin_nontemporal_load(WA + 192 + lane);
        const f32x4 c0 = __builtin_nontemporal_load(WB +   0 + lane);
        const f32x4 c1 = __builtin_nontemporal_load(WB +  64 + lane);
        const f32x4 c2 = __builtin_nontemporal_load(WB + 128 + lane);
        const f32x4 c3 = __builtin_nontemporal_load(WB + 192 + lane);

        const float biasA = bia[(size_t)e * DSZ + myRow];
        const float biasB = bia[(size_t)(e + 1) * DSZ + myRow];

        float pA0 = a0.x * xA.x + a0.y * xA.y + a0.z * xA.z + a0.w * xA.w;
        float pA1 = a1.x * xA.x + a1.y * xA.y + a1.z * xA.z + a1.w * xA.w;
        float pA2 = a2.x * xA.x + a2.y * xA.y + a2.z * xA.z + a2.w * xA.w;
        float pA3 = a3.x * xA.x + a3.y * xA.y + a3.z * xA.z + a3.w * xA.w;
        float pB0 = c0.x * xB.x + c0.y * xB.y + c0.z * xB.z + c0.w * xB.w;
        float pB1 = c1.x * xB.x + c1.y * xB.y + c1.z * xB.z + c1.w * xB.w;
        float pB2 = c2.x * xB.x + c2.y * xB.y + c2.z * xB.z + c2.w * xB.w;
        float pB3 = c3.x * xB.x + c3.y * xB.y + c3.z * xB.z + c3.w * xB.w;

        #pragma unroll
        for (int m = 1; m <= 4; m <<= 1) {
            pA0 += __shfl_xor(pA0, m); pA1 += __shfl_xor(pA1, m);
            pA2 += __shfl_xor(pA2, m); pA3 += __shfl_xor(pA3, m);
            pB0 += __shfl_xor(pB0, m); pB1 += __shfl_xor(pB1, m);
            pB2 += __shfl_xor(pB2, m); pB3 += __shfl_xor(pB3, m);
        }

        if (wr) {
            const float vA = (myIt == 0) ? pA0 : (myIt == 1) ? pA1 : (myIt == 2) ? pA2 : pA3;
            const float vB = (myIt == 0) ? pB0 : (myIt == 1) ? pB1 : (myIt == 2) ? pB2 : pB3;
            atomicAdd(out + (size_t)tA * DSZ + myRow, -(vA + biasA));
            atomicAdd(out + (size_t)tB * DSZ + myRow, -(vB + biasB));
        }
    }
}

extern "C" void kernel_launch(void* const* d_in, const int* in_sizes, int n_in,
                              void* d_out, int out_size, void* d_ws, size_t ws_size,
                              hipStream_t stream) {
    const float* theta = (const float*)d_in[0];
    const float* W     = (const float*)d_in[1];
    const float* b     = (const float*)d_in[2];
    const int*   src   = (const int*)d_in[3];
    const int*   tgt   = (const int*)d_in[4];
    float* out = (float*)d_out;

    // 1) out = theta
    const int n4 = (N_VARS * DSZ) / 4;
    copy_theta_kernel<<<1024, 256, 0, stream>>>((const float4*)theta, (float4*)out, n4);

    // 2) scatter transforms: 4000 waves (one resident batch) x 50 contiguous edges
    const int blocks = NWAVES / 4;  // 4 waves per 256-thread block -> 1000 blocks
    transform_scatter_kernel<<<blocks, 256, 0, stream>>>(theta, W, b, src, tgt, out);
}